// Round 1
// baseline (938.204 us; speedup 1.0000x reference)
//
#include <hip/hip_runtime.h>

typedef __bf16 bf16;
typedef bf16 bf16x4 __attribute__((ext_vector_type(4)));
typedef bf16 bf16x8 __attribute__((ext_vector_type(8)));
typedef float f32x4 __attribute__((ext_vector_type(4)));

#define LOG2E 1.4426950408889634f

__device__ __forceinline__ f32x4 mfma16(bf16x8 a, bf16x8 b, f32x4 c) {
    return __builtin_amdgcn_mfma_f32_16x16x32_bf16(a, b, c, 0, 0, 0);
}

// async global->LDS, 16B per lane. LDS dest is wave-uniform base + lane*16.
__device__ __forceinline__ void async16(const void* g, void* l) {
    __builtin_amdgcn_global_load_lds(
        (const __attribute__((address_space(1))) void*)g,
        (__attribute__((address_space(3))) void*)l, 16, 0, 0);
}

// ---------------------------------------------------------------------------
// prep_w: W{1,2}t[n][k] = (sum_c W_reduce[k][c] * W_qkv[c][n]) * colscale(n)
// colscale folds w_ds*rs (branch1 q) / w_uds*rs (branch2 q) / w_uds (branch2 k);
// bias[z][n] folds b_uds (*rs for q part). rs = d^-0.5 folded into q side.
// grid (8 k-blocks of 64, 48 n-blocks of 16, 2 branches), 256 thr.
// ---------------------------------------------------------------------------
__global__ __launch_bounds__(256) void prep_w(
    const float* __restrict__ Wr, const float* __restrict__ Wq,
    const float* __restrict__ w_ds, const float* __restrict__ w_uds,
    const float* __restrict__ b_uds,
    bf16* __restrict__ W1t, bf16* __restrict__ W2t, float* __restrict__ bias) {
    __shared__ float wq[256][17];
    const int t = threadIdx.x;
    const int k0 = blockIdx.x * 64, n0 = blockIdx.y * 16, z = blockIdx.z;
#pragma unroll
    for (int i = 0; i < 16; i++) {
        int c = i * 16 + (t >> 4);
        wq[c][t & 15] = Wq[c * 768 + n0 + (t & 15)];
    }
    __syncthreads();
    const int j = t & 15, n = n0 + j;
    const float rs = 0.17677669529663687f;  // 1/sqrt(32)
    float scale, bv;
    if (z == 0) {
        scale = (n < 256) ? w_ds[n] * rs : 1.f; bv = 0.f;
    } else if (n < 256) {
        scale = w_uds[n] * rs; bv = b_uds[n] * rs;
    } else if (n < 512) {
        scale = w_uds[n - 256]; bv = b_uds[n - 256];
    } else {
        scale = 1.f; bv = 0.f;
    }
    bf16* Wt = z ? W2t : W1t;
#pragma unroll 1
    for (int i = 0; i < 4; i++) {
        int k = k0 + (t >> 4) * 4 + i;
        float acc = 0.f;
        for (int c = 0; c < 256; c++) acc = fmaf(Wr[k * 256 + c], wq[c][j], acc);
        Wt[n * 512 + k] = (bf16)(acc * scale);
    }
    if (blockIdx.x == 0 && (t >> 4) == 0) bias[z * 768 + n] = bv;
}

// Wpt[n][k] = W_proj[k][n], bf16.  grid 512 blocks x 256 thr.
__global__ void prep_wp(const float* __restrict__ Wp, bf16* __restrict__ Wpt) {
    const int n = blockIdx.x, k = threadIdx.x;
    Wpt[n * 256 + k] = (bf16)Wp[k * 512 + n];
}

// ---------------------------------------------------------------------------
// gemm_qkv v2: Out[m][n] = sum_k X[m][k]*Wt[n][k] + bias[n]; M=73984 K=512 N=768
// BM=64 BN=256 BK=32, 256 thr = 4 waves, each wave owns a 64x64 n-quarter.
// 2-phase double-buffered, ONE barrier per K-step: prefetch (A global->reg,
// B async16) issues before ds_read+MFMA of current tile; A regs->LDS after.
// A tile stride 40 (80B rows: octet reads cover all 32 banks).
// B async16 uses XOR source-swizzle: LDS chunk l of each 16-row group holds
// global chunk ((l&3)-(l>>3))&3; read fetches chunk ((quad+(ln>>1))&3) ->
// bank-spread ds_read_b128 (rule 21: swizzle source AND read, linear dest).
// grid (3 n-blocks, 1156 m-blocks) - n fastest for A-panel L2 reuse.
// ---------------------------------------------------------------------------
__global__ __launch_bounds__(256, 3) void gemm_qkv(
    const float* __restrict__ X, const bf16* __restrict__ Wt,
    const float* __restrict__ biasp, bf16* __restrict__ Out) {
    __shared__ __attribute__((aligned(16))) bf16 As[2][64 * 40];
    __shared__ __attribute__((aligned(16))) bf16 Bs[2][256 * 32];
    const int tid = threadIdx.x;
    const int lane = tid & 63, wave = tid >> 6;
    const int ln = lane & 15, quad = lane >> 4;
    const int bn = blockIdx.x * 256, bm = blockIdx.y * 64;
    const int wn = wave * 64;
    f32x4 acc[4][4] = {};
    float bi[4];
#pragma unroll
    for (int nt = 0; nt < 4; nt++) bi[nt] = biasp[bn + wn + nt * 16 + ln];

    // A staging: 64x32 fp32 tile, 2 float4 per thread (rows sr, sr+32)
    const int sr = tid >> 3;               // 0..31
    const int sc = (tid & 7) * 4;          // 0,4,..,28
    const float* xp0 = &X[(bm + sr) * 512 + sc];
    const float* xp1 = &X[(bm + sr + 32) * 512 + sc];
    // B staging: 4 async16 per wave (16 rows each), swizzled source chunk
    const int bq8 = (((lane & 3) - (lane >> 3)) & 3) * 8;
    const int brow = bn + wn + (lane >> 2);
    // read-side swizzle chunk offset (elements)
    const int rq = ((quad + (ln >> 1)) & 3) * 8;

    // prologue: stage K-tile 0 into buffer 0
    {
        float4 v0 = *(const float4*)xp0;
        float4 v1 = *(const float4*)xp1;
        bf16x4 w0 = {(bf16)v0.x, (bf16)v0.y, (bf16)v0.z, (bf16)v0.w};
        bf16x4 w1 = {(bf16)v1.x, (bf16)v1.y, (bf16)v1.z, (bf16)v1.w};
        *(bf16x4*)&As[0][sr * 40 + sc] = w0;
        *(bf16x4*)&As[0][(sr + 32) * 40 + sc] = w1;
#pragma unroll
        for (int jg = 0; jg < 4; jg++)
            async16(&Wt[(brow + jg * 16) * 512 + bq8],
                    &Bs[0][(wn + jg * 16) * 32]);
    }
    __syncthreads();

    int cur = 0;
#pragma unroll 1
    for (int kb = 0; kb < 512; kb += 32) {
        const int kn = kb + 32;
        const int nxt = cur ^ 1;
        float4 v0, v1;
        if (kn < 512) {
            v0 = *(const float4*)(xp0 + kn);
            v1 = *(const float4*)(xp1 + kn);
#pragma unroll
            for (int jg = 0; jg < 4; jg++)
                async16(&Wt[(brow + jg * 16) * 512 + kn + bq8],
                        &Bs[nxt][(wn + jg * 16) * 32]);
        }
        bf16x8 a[4], b[4];
#pragma unroll
        for (int mt = 0; mt < 4; mt++)
            a[mt] = *(const bf16x8*)&As[cur][(mt * 16 + ln) * 40 + quad * 8];
#pragma unroll
        for (int nt = 0; nt < 4; nt++)
            b[nt] = *(const bf16x8*)&Bs[cur][(wn + nt * 16 + ln) * 32 + rq];
#pragma unroll
        for (int mt = 0; mt < 4; mt++)
#pragma unroll
            for (int nt = 0; nt < 4; nt++)
                acc[mt][nt] = mfma16(a[mt], b[nt], acc[mt][nt]);
        if (kn < 512) {
            bf16x4 w0 = {(bf16)v0.x, (bf16)v0.y, (bf16)v0.z, (bf16)v0.w};
            bf16x4 w1 = {(bf16)v1.x, (bf16)v1.y, (bf16)v1.z, (bf16)v1.w};
            *(bf16x4*)&As[nxt][sr * 40 + sc] = w0;
            *(bf16x4*)&As[nxt][(sr + 32) * 40 + sc] = w1;
        }
        __syncthreads();
        cur = nxt;
    }
#pragma unroll
    for (int mt = 0; mt < 4; mt++)
#pragma unroll
        for (int nt = 0; nt < 4; nt++) {
            int col = bn + wn + nt * 16 + ln;
#pragma unroll
            for (int r = 0; r < 4; r++) {
                int row = bm + mt * 16 + quad * 4 + r;
                Out[row * 768 + col] = (bf16)(acc[mt][nt][r] + bi[nt]);
            }
        }
}

// ---------------------------------------------------------------------------
// gemm_proj v2: Y[m][n] = sum_k A[m][k]*Wt[n][k] + bp[n]; M=73984 K=256 N=512
// 128x128 tile, 2-phase double-buffered single-barrier, both operands via
// async16 with the same source/read XOR swizzle as gemm_qkv's B.
// grid (4 n-blocks, 578 m-blocks).
// ---------------------------------------------------------------------------
__global__ __launch_bounds__(256, 4) void gemm_proj(
    const bf16* __restrict__ A, const bf16* __restrict__ Wt,
    const float* __restrict__ bp, float* __restrict__ Y) {
    __shared__ __attribute__((aligned(16))) bf16 As[2][128 * 32];
    __shared__ __attribute__((aligned(16))) bf16 Bs[2][128 * 32];
    const int tid = threadIdx.x;
    const int lane = tid & 63, wave = tid >> 6;
    const int ln = lane & 15, quad = lane >> 4;
    const int bn = blockIdx.x * 128, bm = blockIdx.y * 128;
    const int wm = (wave & 1) * 64, wn = (wave >> 1) * 64;
    f32x4 acc[4][4] = {};
    float bi[4];
#pragma unroll
    for (int nt = 0; nt < 4; nt++) bi[nt] = bp[bn + wn + nt * 16 + ln];
    const int bq8 = (((lane & 3) - (lane >> 3)) & 3) * 8;  // src chunk swizzle
    const int arow = bm + wave * 32 + (lane >> 2);
    const int brow = bn + wave * 32 + (lane >> 2);
    const int rq = ((quad + (ln >> 1)) & 3) * 8;           // read chunk swizzle
    bf16* as0 = &As[0][(wave * 32) * 32];
    bf16* as1 = &As[0][(wave * 32 + 16) * 32];
    bf16* bs0 = &Bs[0][(wave * 32) * 32];
    bf16* bs1 = &Bs[0][(wave * 32 + 16) * 32];
    const int bufstride = 128 * 32;

    // prologue: K-tile 0 into buffer 0
    async16(&A[arow * 256 + bq8], as0);
    async16(&A[(arow + 16) * 256 + bq8], as1);
    async16(&Wt[brow * 256 + bq8], bs0);
    async16(&Wt[(brow + 16) * 256 + bq8], bs1);
    __syncthreads();

    int cur = 0;
#pragma unroll 1
    for (int kb = 0; kb < 256; kb += 32) {
        const int kn = kb + 32;
        const int nxt = cur ^ 1;
        if (kn < 256) {
            async16(&A[arow * 256 + kn + bq8], as0 + nxt * bufstride);
            async16(&A[(arow + 16) * 256 + kn + bq8], as1 + nxt * bufstride);
            async16(&Wt[brow * 256 + kn + bq8], bs0 + nxt * bufstride);
            async16(&Wt[(brow + 16) * 256 + kn + bq8], bs1 + nxt * bufstride);
        }
        bf16x8 a[4], b[4];
#pragma unroll
        for (int mt = 0; mt < 4; mt++)
            a[mt] = *(const bf16x8*)&As[cur][(wm + mt * 16 + ln) * 32 + rq];
#pragma unroll
        for (int nt = 0; nt < 4; nt++)
            b[nt] = *(const bf16x8*)&Bs[cur][(wn + nt * 16 + ln) * 32 + rq];
#pragma unroll
        for (int mt = 0; mt < 4; mt++)
#pragma unroll
            for (int nt = 0; nt < 4; nt++)
                acc[mt][nt] = mfma16(a[mt], b[nt], acc[mt][nt]);
        __syncthreads();
        cur = nxt;
    }
#pragma unroll
    for (int mt = 0; mt < 4; mt++)
#pragma unroll
        for (int nt = 0; nt < 4; nt++) {
            int col = bn + wn + nt * 16 + ln;
#pragma unroll
            for (int r = 0; r < 4; r++) {
                int row = bm + wm + mt * 16 + quad * 4 + r;
                Y[row * 512 + col] = acc[mt][nt][r] + bi[nt];
            }
        }
}

// ---------------------------------------------------------------------------
// attn: per (chunk, batch) block, 4 waves, each wave does heads {w, w+4}.
// QKV row layout: [q(256) | k(256) | v(256)], all scales/bias pre-folded.
// S = Q·K^T (scale folded), softmax over keys, O = P·V, write o[b,n,h*32+d].
// All LDS is wave-private -> no barriers.
// ---------------------------------------------------------------------------
__global__ __launch_bounds__(256) void attn(const bf16* __restrict__ QKV,
                                            bf16* __restrict__ O) {
    __shared__ __attribute__((aligned(16))) bf16 vT[4][32 * 104];
    __shared__ __attribute__((aligned(16))) bf16 P[4][16 * 104];
    const int tid = threadIdx.x;
    const int lane = tid & 63, wave = tid >> 6;
    const int ln = lane & 15, quad = lane >> 4;
    const int chunk = blockIdx.x, b = blockIdx.y;
    const int s = chunk * 73;
    const int mc = min(289 - s, 73);  // chunk length (73,73,73,70)
    const int rowbase = b * 289 + s;
    bf16* vTw = &vT[wave][0];
    bf16* Pw = &P[wave][0];
    const f32x4 zero4 = {0.f, 0.f, 0.f, 0.f};

    // zero P pad cols [80,96) once (read by PV m-chunk 2, never written otherwise)
    {
        bf16x4 z = {(bf16)0.f, (bf16)0.f, (bf16)0.f, (bf16)0.f};
        *(bf16x4*)&Pw[(lane >> 2) * 104 + 80 + (lane & 3) * 4] = z;
    }

#pragma unroll 1
    for (int hi = 0; hi < 2; hi++) {
        const int h = wave + hi * 4;
        const int cq = h * 32, ck = 256 + h * 32, cv = 512 + h * 32;

        // stage V transposed: vT[d][m].  NOTE: cover m=0..95 (clamped) so the
        // vf[*][2] fragment (m 64..95) never reads uninitialized LDS — the
        // matching P cols [80,96) are zero, but 0*NaN-garbage = NaN (round-1 bug).
#pragma unroll
        for (int p5 = 0; p5 < 6; p5++) {
            int m = p5 * 16 + (lane >> 2);
            int mr = min(m, mc - 1);
            bf16x8 v8 = *(const bf16x8*)&QKV[(rowbase + mr) * 768 + cv + (lane & 3) * 8];
            int d0 = (lane & 3) * 8;
#pragma unroll
            for (int j = 0; j < 8; j++) vTw[(d0 + j) * 104 + m] = v8[j];
        }
        // K fragments (B-operand pattern: lane&15 -> key row, quad*8 -> d)
        bf16x8 kf[5];
#pragma unroll
        for (int mt = 0; mt < 5; mt++) {
            int mr = min(mt * 16 + ln, mc - 1);
            kf[mt] = *(const bf16x8*)&QKV[(rowbase + mr) * 768 + ck + quad * 8];
        }
        // V fragments (B-operand: lane&15 -> d row of vT, quad*8 -> m)
        bf16x8 vf[2][3];
#pragma unroll
        for (int dt = 0; dt < 2; dt++)
#pragma unroll
            for (int mk = 0; mk < 3; mk++)
                vf[dt][mk] = *(const bf16x8*)&vTw[(dt * 16 + ln) * 104 + mk * 32 + quad * 8];

#pragma unroll 1
        for (int nt = 0; nt < 5; nt++) {
            int qr = min(nt * 16 + ln, mc - 1);
            bf16x8 qf = *(const bf16x8*)&QKV[(rowbase + qr) * 768 + cq + quad * 8];
            f32x4 S[5];
#pragma unroll
            for (int mt = 0; mt < 5; mt++) S[mt] = mfma16(qf, kf[mt], zero4);
            // mask padded key columns (C layout: col = lane&15)
#pragma unroll
            for (int mt = 0; mt < 5; mt++)
                if (mt * 16 + ln >= mc) {
                    S[mt][0] = -1e30f; S[mt][1] = -1e30f;
                    S[mt][2] = -1e30f; S[mt][3] = -1e30f;
                }
            // row softmax: rows = quad*4+r, reduce over 16 col-lanes + 5 tiles
            float mxv[4], sm[4];
#pragma unroll
            for (int r = 0; r < 4; r++) {
                float m0 = S[0][r];
#pragma unroll
                for (int mt = 1; mt < 5; mt++) m0 = fmaxf(m0, S[mt][r]);
                m0 = fmaxf(m0, __shfl_xor(m0, 1));
                m0 = fmaxf(m0, __shfl_xor(m0, 2));
                m0 = fmaxf(m0, __shfl_xor(m0, 4));
                m0 = fmaxf(m0, __shfl_xor(m0, 8));
                mxv[r] = m0;
                sm[r] = 0.f;
            }
#pragma unroll
            for (int mt = 0; mt < 5; mt++)
#pragma unroll
                for (int r = 0; r < 4; r++) {
                    float p = exp2f((S[mt][r] - mxv[r]) * LOG2E);
                    sm[r] += p;
                    Pw[(quad * 4 + r) * 104 + mt * 16 + ln] = (bf16)p;
                }
#pragma unroll
            for (int r = 0; r < 4; r++) {
                float t = sm[r];
                t += __shfl_xor(t, 1);
                t += __shfl_xor(t, 2);
                t += __shfl_xor(t, 4);
                t += __shfl_xor(t, 8);
                sm[r] = 1.0f / t;
            }
            // PV: A = P rows (lane&15 -> n, quad*8 -> m), B = vf
            f32x4 o0 = zero4, o1 = zero4;
#pragma unroll
            for (int mk = 0; mk < 3; mk++) {
                bf16x8 pa = *(const bf16x8*)&Pw[ln * 104 + mk * 32 + quad * 8];
                o0 = mfma16(pa, vf[0][mk], o0);
                o1 = mfma16(pa, vf[1][mk], o1);
            }
#pragma unroll
            for (int r = 0; r < 4; r++) {
                int nl = nt * 16 + quad * 4 + r;
                if (nl < mc) {
                    int orow = (rowbase + nl) * 256 + h * 32;
                    O[orow + ln] = (bf16)(o0[r] * sm[r]);
                    O[orow + 16 + ln] = (bf16)(o1[r] * sm[r]);
                }
            }
        }
    }
}

// ---------------------------------------------------------------------------
extern "C" void kernel_launch(void* const* d_in, const int* in_sizes, int n_in,
                              void* d_out, int out_size, void* d_ws, size_t ws_size,
                              hipStream_t stream) {
    (void)in_sizes; (void)n_in; (void)out_size;
    const float* x1 = (const float*)d_in[0];
    const float* x2 = (const float*)d_in[1];
    const float* Wr = (const float*)d_in[2];
    const float* Wq = (const float*)d_in[3];
    const float* Wp = (const float*)d_in[4];
    const float* bp = (const float*)d_in[5];
    const float* w_ds = (const float*)d_in[6];
    const float* w_uds = (const float*)d_in[7];
    const float* b_uds = (const float*)d_in[8];

    char* ws = (char*)d_ws;
    bf16* W1t = (bf16*)(ws);                     //  786432 B
    bf16* W2t = (bf16*)(ws + 786432);            //  786432 B
    bf16* Wpt = (bf16*)(ws + 1572864);           //  262144 B
    float* bias = (float*)(ws + 1835008);        //    6144 B
    bf16* ob = (bf16*)(ws + 1841152);            // 37879808 B  (o buffer)
    float* out = (float*)d_out;
    // qkv scratch: prefer d_ws when it's big enough (deterministic choice per
    // session -> graph-capture safe); else use the not-yet-written second half
    // of d_out (fully consumed by attn before gemm_proj(br1) overwrites it).
    bf16* qkv;
    if (ws_size >= (size_t)39720960 + 113639424) {
        qkv = (bf16*)(ws + 39720960);
    } else {
        qkv = (bf16*)(out + 37879808);           // 113639424 B
    }

    prep_w<<<dim3(8, 48, 2), 256, 0, stream>>>(Wr, Wq, w_ds, w_uds, b_uds, W1t, W2t, bias);
    prep_wp<<<dim3(512), 256, 0, stream>>>(Wp, Wpt);
    for (int br = 0; br < 2; br++) {
        const float* X = br ? x2 : x1;
        const bf16* Wt = br ? W2t : W1t;
        gemm_qkv<<<dim3(3, 1156), 256, 0, stream>>>(X, Wt, bias + br * 768, qkv);
        attn<<<dim3(4, 256), 256, 0, stream>>>(qkv, ob);
        gemm_proj<<<dim3(4, 578), 256, 0, stream>>>(ob, Wpt, bp, out + (size_t)br * 37879808);
    }
}

// Round 2
// 901.986 us; speedup vs baseline: 1.0402x; 1.0402x over previous
//
#include <hip/hip_runtime.h>

typedef __bf16 bf16;
typedef bf16 bf16x4 __attribute__((ext_vector_type(4)));
typedef bf16 bf16x8 __attribute__((ext_vector_type(8)));
typedef float f32x4 __attribute__((ext_vector_type(4)));

#define LOG2E 1.4426950408889634f

__device__ __forceinline__ f32x4 mfma16(bf16x8 a, bf16x8 b, f32x4 c) {
    return __builtin_amdgcn_mfma_f32_16x16x32_bf16(a, b, c, 0, 0, 0);
}

// async global->LDS, 16B per lane. LDS dest is wave-uniform base + lane*16.
__device__ __forceinline__ void async16(const void* g, void* l) {
    __builtin_amdgcn_global_load_lds(
        (const __attribute__((address_space(1))) void*)g,
        (__attribute__((address_space(3))) void*)l, 16, 0, 0);
}

// ---------------------------------------------------------------------------
// prep_w: W{1,2}t[n][k] = (sum_c W_reduce[k][c] * W_qkv[c][n]) * colscale(n)
// colscale folds w_ds*rs (branch1 q) / w_uds*rs (branch2 q) / w_uds (branch2 k);
// bias[z][n] folds b_uds (*rs for q part). rs = d^-0.5 folded into q side.
// grid (8 k-blocks of 64, 48 n-blocks of 16, 2 branches), 256 thr.
// ---------------------------------------------------------------------------
__global__ __launch_bounds__(256) void prep_w(
    const float* __restrict__ Wr, const float* __restrict__ Wq,
    const float* __restrict__ w_ds, const float* __restrict__ w_uds,
    const float* __restrict__ b_uds,
    bf16* __restrict__ W1t, bf16* __restrict__ W2t, float* __restrict__ bias) {
    __shared__ float wq[256][17];
    const int t = threadIdx.x;
    const int k0 = blockIdx.x * 64, n0 = blockIdx.y * 16, z = blockIdx.z;
#pragma unroll
    for (int i = 0; i < 16; i++) {
        int c = i * 16 + (t >> 4);
        wq[c][t & 15] = Wq[c * 768 + n0 + (t & 15)];
    }
    __syncthreads();
    const int j = t & 15, n = n0 + j;
    const float rs = 0.17677669529663687f;  // 1/sqrt(32)
    float scale, bv;
    if (z == 0) {
        scale = (n < 256) ? w_ds[n] * rs : 1.f; bv = 0.f;
    } else if (n < 256) {
        scale = w_uds[n] * rs; bv = b_uds[n] * rs;
    } else if (n < 512) {
        scale = w_uds[n - 256]; bv = b_uds[n - 256];
    } else {
        scale = 1.f; bv = 0.f;
    }
    bf16* Wt = z ? W2t : W1t;
#pragma unroll 1
    for (int i = 0; i < 4; i++) {
        int k = k0 + (t >> 4) * 4 + i;
        float acc = 0.f;
        for (int c = 0; c < 256; c++) acc = fmaf(Wr[k * 256 + c], wq[c][j], acc);
        Wt[n * 512 + k] = (bf16)(acc * scale);
    }
    if (blockIdx.x == 0 && (t >> 4) == 0) bias[z * 768 + n] = bv;
}

// Wpt[n][k] = W_proj[k][n], bf16.  grid 512 blocks x 256 thr.
__global__ void prep_wp(const float* __restrict__ Wp, bf16* __restrict__ Wpt) {
    const int n = blockIdx.x, k = threadIdx.x;
    Wpt[n * 256 + k] = (bf16)Wp[k * 512 + n];
}

// ---------------------------------------------------------------------------
// xcast: fp32 -> bf16, vectorized 8/thread, grid (2048, 2).
// Moves the fp32->bf16 conversion OFF the GEMM critical path so gemm_qkv can
// use global_load_lds for both operands (m151: reg-staging costs ~25%).
// ---------------------------------------------------------------------------
__global__ __launch_bounds__(256) void xcast(const float* __restrict__ X1,
                                             const float* __restrict__ X2,
                                             bf16* __restrict__ O1,
                                             bf16* __restrict__ O2) {
    const float* X = blockIdx.y ? X2 : X1;
    bf16* O = blockIdx.y ? O2 : O1;
    const long total = 37879808;  // 73984 * 512
    const long stride = (long)gridDim.x * 256 * 8;
    for (long i = ((long)blockIdx.x * 256 + threadIdx.x) * 8; i < total; i += stride) {
        float4 a = *(const float4*)&X[i];
        float4 b = *(const float4*)&X[i + 4];
        bf16x8 w = {(bf16)a.x, (bf16)a.y, (bf16)a.z, (bf16)a.w,
                    (bf16)b.x, (bf16)b.y, (bf16)b.z, (bf16)b.w};
        *(bf16x8*)&O[i] = w;
    }
}

// ---------------------------------------------------------------------------
// gemm_qkv v3: Out[m][n] = sum_k X[m][k]*Wt[n][k] + bias[n]; M=73984 K=512 N=768
// Pure bf16 m97 structure: 128x128 tile, BK=32, both operands via async16,
// linear [128][32] LDS, double-buffered, ONE barrier per K-step (T3 minimum:
// issue next-tile stage before current ds_read+MFMA).  32 KB LDS -> 4 blk/CU.
// grid (6 n-blocks, 578 m-blocks) - n fastest, A panel L3-resident.
// ---------------------------------------------------------------------------
__global__ __launch_bounds__(256, 4) void gemm_qkv(
    const bf16* __restrict__ X, const bf16* __restrict__ Wt,
    const float* __restrict__ biasp, bf16* __restrict__ Out) {
    __shared__ __attribute__((aligned(16))) bf16 As[2][128 * 32];
    __shared__ __attribute__((aligned(16))) bf16 Bs[2][128 * 32];
    const int tid = threadIdx.x;
    const int lane = tid & 63, wave = tid >> 6;
    const int ln = lane & 15, quad = lane >> 4;
    const int bn = blockIdx.x * 128, bm = blockIdx.y * 128;
    const int wm = (wave & 1) * 64, wn = (wave >> 1) * 64;
    f32x4 acc[4][4] = {};
    float bi[4];
#pragma unroll
    for (int nt = 0; nt < 4; nt++) bi[nt] = biasp[bn + wn + nt * 16 + ln];
    const int arow = bm + wave * 32 + (lane >> 2);
    const int brow = bn + wave * 32 + (lane >> 2);
    const int c0 = (lane & 3) * 8;
    bf16* as0 = &As[0][(wave * 32) * 32];
    bf16* as1 = &As[0][(wave * 32 + 16) * 32];
    bf16* bs0 = &Bs[0][(wave * 32) * 32];
    bf16* bs1 = &Bs[0][(wave * 32 + 16) * 32];
    const int bufstride = 128 * 32;

    // prologue: K-tile 0 into buffer 0
    async16(&X[arow * 512 + c0], as0);
    async16(&X[(arow + 16) * 512 + c0], as1);
    async16(&Wt[brow * 512 + c0], bs0);
    async16(&Wt[(brow + 16) * 512 + c0], bs1);
    __syncthreads();

    int cur = 0;
#pragma unroll 1
    for (int kb = 0; kb < 512; kb += 32) {
        const int kn = kb + 32;
        const int nxt = cur ^ 1;
        if (kn < 512) {
            async16(&X[arow * 512 + kn + c0], as0 + nxt * bufstride);
            async16(&X[(arow + 16) * 512 + kn + c0], as1 + nxt * bufstride);
            async16(&Wt[brow * 512 + kn + c0], bs0 + nxt * bufstride);
            async16(&Wt[(brow + 16) * 512 + kn + c0], bs1 + nxt * bufstride);
        }
        bf16x8 a[4], b[4];
#pragma unroll
        for (int mt = 0; mt < 4; mt++)
            a[mt] = *(const bf16x8*)&As[cur][(wm + mt * 16 + ln) * 32 + quad * 8];
#pragma unroll
        for (int nt = 0; nt < 4; nt++)
            b[nt] = *(const bf16x8*)&Bs[cur][(wn + nt * 16 + ln) * 32 + quad * 8];
#pragma unroll
        for (int mt = 0; mt < 4; mt++)
#pragma unroll
            for (int nt = 0; nt < 4; nt++)
                acc[mt][nt] = mfma16(a[mt], b[nt], acc[mt][nt]);
        __syncthreads();
        cur = nxt;
    }
#pragma unroll
    for (int mt = 0; mt < 4; mt++)
#pragma unroll
        for (int nt = 0; nt < 4; nt++) {
            int col = bn + wn + nt * 16 + ln;
#pragma unroll
            for (int r = 0; r < 4; r++) {
                int row = bm + wm + mt * 16 + quad * 4 + r;
                Out[row * 768 + col] = (bf16)(acc[mt][nt][r] + bi[nt]);
            }
        }
}

// ---------------------------------------------------------------------------
// gemm_proj v3: Y[m][n] = sum_k A[m][k]*Wt[n][k] + bp[n]; M=73984 K=256 N=512
// Same structure as gemm_qkv v3 (linear addressing, dbuf single-barrier).
// grid (4 n-blocks, 578 m-blocks).
// ---------------------------------------------------------------------------
__global__ __launch_bounds__(256, 4) void gemm_proj(
    const bf16* __restrict__ A, const bf16* __restrict__ Wt,
    const float* __restrict__ bp, float* __restrict__ Y) {
    __shared__ __attribute__((aligned(16))) bf16 As[2][128 * 32];
    __shared__ __attribute__((aligned(16))) bf16 Bs[2][128 * 32];
    const int tid = threadIdx.x;
    const int lane = tid & 63, wave = tid >> 6;
    const int ln = lane & 15, quad = lane >> 4;
    const int bn = blockIdx.x * 128, bm = blockIdx.y * 128;
    const int wm = (wave & 1) * 64, wn = (wave >> 1) * 64;
    f32x4 acc[4][4] = {};
    float bi[4];
#pragma unroll
    for (int nt = 0; nt < 4; nt++) bi[nt] = bp[bn + wn + nt * 16 + ln];
    const int arow = bm + wave * 32 + (lane >> 2);
    const int brow = bn + wave * 32 + (lane >> 2);
    const int c0 = (lane & 3) * 8;
    bf16* as0 = &As[0][(wave * 32) * 32];
    bf16* as1 = &As[0][(wave * 32 + 16) * 32];
    bf16* bs0 = &Bs[0][(wave * 32) * 32];
    bf16* bs1 = &Bs[0][(wave * 32 + 16) * 32];
    const int bufstride = 128 * 32;

    // prologue: K-tile 0 into buffer 0
    async16(&A[arow * 256 + c0], as0);
    async16(&A[(arow + 16) * 256 + c0], as1);
    async16(&Wt[brow * 256 + c0], bs0);
    async16(&Wt[(brow + 16) * 256 + c0], bs1);
    __syncthreads();

    int cur = 0;
#pragma unroll 1
    for (int kb = 0; kb < 256; kb += 32) {
        const int kn = kb + 32;
        const int nxt = cur ^ 1;
        if (kn < 256) {
            async16(&A[arow * 256 + kn + c0], as0 + nxt * bufstride);
            async16(&A[(arow + 16) * 256 + kn + c0], as1 + nxt * bufstride);
            async16(&Wt[brow * 256 + kn + c0], bs0 + nxt * bufstride);
            async16(&Wt[(brow + 16) * 256 + kn + c0], bs1 + nxt * bufstride);
        }
        bf16x8 a[4], b[4];
#pragma unroll
        for (int mt = 0; mt < 4; mt++)
            a[mt] = *(const bf16x8*)&As[cur][(wm + mt * 16 + ln) * 32 + quad * 8];
#pragma unroll
        for (int nt = 0; nt < 4; nt++)
            b[nt] = *(const bf16x8*)&Bs[cur][(wn + nt * 16 + ln) * 32 + quad * 8];
#pragma unroll
        for (int mt = 0; mt < 4; mt++)
#pragma unroll
            for (int nt = 0; nt < 4; nt++)
                acc[mt][nt] = mfma16(a[mt], b[nt], acc[mt][nt]);
        __syncthreads();
        cur = nxt;
    }
#pragma unroll
    for (int mt = 0; mt < 4; mt++)
#pragma unroll
        for (int nt = 0; nt < 4; nt++) {
            int col = bn + wn + nt * 16 + ln;
#pragma unroll
            for (int r = 0; r < 4; r++) {
                int row = bm + wm + mt * 16 + quad * 4 + r;
                Y[row * 512 + col] = acc[mt][nt][r] + bi[nt];
            }
        }
}

// ---------------------------------------------------------------------------
// attn: per (chunk, batch) block, 4 waves, each wave does heads {w, w+4}.
// QKV row layout: [q(256) | k(256) | v(256)], all scales/bias pre-folded.
// S = Q·K^T (scale folded), softmax over keys, O = P·V, write o[b,n,h*32+d].
// All LDS is wave-private -> no barriers.
// ---------------------------------------------------------------------------
__global__ __launch_bounds__(256) void attn(const bf16* __restrict__ QKV,
                                            bf16* __restrict__ O) {
    __shared__ __attribute__((aligned(16))) bf16 vT[4][32 * 104];
    __shared__ __attribute__((aligned(16))) bf16 P[4][16 * 104];
    const int tid = threadIdx.x;
    const int lane = tid & 63, wave = tid >> 6;
    const int ln = lane & 15, quad = lane >> 4;
    const int chunk = blockIdx.x, b = blockIdx.y;
    const int s = chunk * 73;
    const int mc = min(289 - s, 73);  // chunk length (73,73,73,70)
    const int rowbase = b * 289 + s;
    bf16* vTw = &vT[wave][0];
    bf16* Pw = &P[wave][0];
    const f32x4 zero4 = {0.f, 0.f, 0.f, 0.f};

    // zero P pad cols [80,96) once (read by PV m-chunk 2, never written otherwise)
    {
        bf16x4 z = {(bf16)0.f, (bf16)0.f, (bf16)0.f, (bf16)0.f};
        *(bf16x4*)&Pw[(lane >> 2) * 104 + 80 + (lane & 3) * 4] = z;
    }

#pragma unroll 1
    for (int hi = 0; hi < 2; hi++) {
        const int h = wave + hi * 4;
        const int cq = h * 32, ck = 256 + h * 32, cv = 512 + h * 32;

        // stage V transposed: vT[d][m].  NOTE: cover m=0..95 (clamped) so the
        // vf[*][2] fragment (m 64..95) never reads uninitialized LDS — the
        // matching P cols [80,96) are zero, but 0*NaN-garbage = NaN (round-1 bug).
#pragma unroll
        for (int p5 = 0; p5 < 6; p5++) {
            int m = p5 * 16 + (lane >> 2);
            int mr = min(m, mc - 1);
            bf16x8 v8 = *(const bf16x8*)&QKV[(rowbase + mr) * 768 + cv + (lane & 3) * 8];
            int d0 = (lane & 3) * 8;
#pragma unroll
            for (int j = 0; j < 8; j++) vTw[(d0 + j) * 104 + m] = v8[j];
        }
        // K fragments (B-operand pattern: lane&15 -> key row, quad*8 -> d)
        bf16x8 kf[5];
#pragma unroll
        for (int mt = 0; mt < 5; mt++) {
            int mr = min(mt * 16 + ln, mc - 1);
            kf[mt] = *(const bf16x8*)&QKV[(rowbase + mr) * 768 + ck + quad * 8];
        }
        // V fragments (B-operand: lane&15 -> d row of vT, quad*8 -> m)
        bf16x8 vf[2][3];
#pragma unroll
        for (int dt = 0; dt < 2; dt++)
#pragma unroll
            for (int mk = 0; mk < 3; mk++)
                vf[dt][mk] = *(const bf16x8*)&vTw[(dt * 16 + ln) * 104 + mk * 32 + quad * 8];

#pragma unroll 1
        for (int nt = 0; nt < 5; nt++) {
            int qr = min(nt * 16 + ln, mc - 1);
            bf16x8 qf = *(const bf16x8*)&QKV[(rowbase + qr) * 768 + cq + quad * 8];
            f32x4 S[5];
#pragma unroll
            for (int mt = 0; mt < 5; mt++) S[mt] = mfma16(qf, kf[mt], zero4);
            // mask padded key columns (C layout: col = lane&15)
#pragma unroll
            for (int mt = 0; mt < 5; mt++)
                if (mt * 16 + ln >= mc) {
                    S[mt][0] = -1e30f; S[mt][1] = -1e30f;
                    S[mt][2] = -1e30f; S[mt][3] = -1e30f;
                }
            // row softmax: rows = quad*4+r, reduce over 16 col-lanes + 5 tiles
            float mxv[4], sm[4];
#pragma unroll
            for (int r = 0; r < 4; r++) {
                float m0 = S[0][r];
#pragma unroll
                for (int mt = 1; mt < 5; mt++) m0 = fmaxf(m0, S[mt][r]);
                m0 = fmaxf(m0, __shfl_xor(m0, 1));
                m0 = fmaxf(m0, __shfl_xor(m0, 2));
                m0 = fmaxf(m0, __shfl_xor(m0, 4));
                m0 = fmaxf(m0, __shfl_xor(m0, 8));
                mxv[r] = m0;
                sm[r] = 0.f;
            }
#pragma unroll
            for (int mt = 0; mt < 5; mt++)
#pragma unroll
                for (int r = 0; r < 4; r++) {
                    float p = exp2f((S[mt][r] - mxv[r]) * LOG2E);
                    sm[r] += p;
                    Pw[(quad * 4 + r) * 104 + mt * 16 + ln] = (bf16)p;
                }
#pragma unroll
            for (int r = 0; r < 4; r++) {
                float t = sm[r];
                t += __shfl_xor(t, 1);
                t += __shfl_xor(t, 2);
                t += __shfl_xor(t, 4);
                t += __shfl_xor(t, 8);
                sm[r] = 1.0f / t;
            }
            // PV: A = P rows (lane&15 -> n, quad*8 -> m), B = vf
            f32x4 o0 = zero4, o1 = zero4;
#pragma unroll
            for (int mk = 0; mk < 3; mk++) {
                bf16x8 pa = *(const bf16x8*)&Pw[ln * 104 + mk * 32 + quad * 8];
                o0 = mfma16(pa, vf[0][mk], o0);
                o1 = mfma16(pa, vf[1][mk], o1);
            }
#pragma unroll
            for (int r = 0; r < 4; r++) {
                int nl = nt * 16 + quad * 4 + r;
                if (nl < mc) {
                    int orow = (rowbase + nl) * 256 + h * 32;
                    O[orow + ln] = (bf16)(o0[r] * sm[r]);
                    O[orow + 16 + ln] = (bf16)(o1[r] * sm[r]);
                }
            }
        }
    }
}

// ---------------------------------------------------------------------------
// Buffer plan (all sizes bytes):
//   ws:   W1t 786432 | W2t 786432 | Wpt 262144 | bias 6144 | ob 37879808
//   d_out (303038464): [0 : 75759616)           Xb1 (bf16 cast of x1)
//                      [75759616 : 151519232)   Xb2 (bf16 cast of x2)
//                      [151519232 : 265158656)  qkv (ping-pong, both branches)
//   Launch order guarantees: Xb1/Xb2 consumed by the two gemm_qkv's before
//   gemm_proj(br0) overwrites [0:151519232) with y1; qkv(br0) consumed by
//   attn(br0) before gemm_qkv(br1) rewrites it; y2 written last over qkv.
// ---------------------------------------------------------------------------
extern "C" void kernel_launch(void* const* d_in, const int* in_sizes, int n_in,
                              void* d_out, int out_size, void* d_ws, size_t ws_size,
                              hipStream_t stream) {
    (void)in_sizes; (void)n_in; (void)out_size; (void)ws_size;
    const float* x1 = (const float*)d_in[0];
    const float* x2 = (const float*)d_in[1];
    const float* Wr = (const float*)d_in[2];
    const float* Wq = (const float*)d_in[3];
    const float* Wp = (const float*)d_in[4];
    const float* bp = (const float*)d_in[5];
    const float* w_ds = (const float*)d_in[6];
    const float* w_uds = (const float*)d_in[7];
    const float* b_uds = (const float*)d_in[8];

    char* ws = (char*)d_ws;
    bf16* W1t = (bf16*)(ws);                     //  786432 B
    bf16* W2t = (bf16*)(ws + 786432);            //  786432 B
    bf16* Wpt = (bf16*)(ws + 1572864);           //  262144 B
    float* bias = (float*)(ws + 1835008);        //    6144 B
    bf16* ob = (bf16*)(ws + 1841152);            // 37879808 B  (o buffer)
    float* out = (float*)d_out;
    char* outc = (char*)d_out;
    bf16* Xb1 = (bf16*)(outc);                   // 75759616 B
    bf16* Xb2 = (bf16*)(outc + 75759616);        // 75759616 B
    bf16* qkv = (bf16*)(outc + 151519232);       // 113639424 B

    prep_w<<<dim3(8, 48, 2), 256, 0, stream>>>(Wr, Wq, w_ds, w_uds, b_uds, W1t, W2t, bias);
    prep_wp<<<dim3(512), 256, 0, stream>>>(Wp, Wpt);
    xcast<<<dim3(2048, 2), 256, 0, stream>>>(x1, x2, Xb1, Xb2);

    gemm_qkv<<<dim3(6, 578), 256, 0, stream>>>(Xb1, W1t, bias, qkv);
    attn<<<dim3(4, 256), 256, 0, stream>>>(qkv, ob);
    gemm_qkv<<<dim3(6, 578), 256, 0, stream>>>(Xb2, W2t, bias + 768, qkv);
    gemm_proj<<<dim3(4, 578), 256, 0, stream>>>(ob, Wpt, bp, out);
    attn<<<dim3(4, 256), 256, 0, stream>>>(qkv, ob);
    gemm_proj<<<dim3(4, 578), 256, 0, stream>>>(ob, Wpt, bp, out + (size_t)37879808);
}

// Round 3
// 897.029 us; speedup vs baseline: 1.0459x; 1.0055x over previous
//
#include <hip/hip_runtime.h>

typedef __bf16 bf16;
typedef bf16 bf16x4 __attribute__((ext_vector_type(4)));
typedef bf16 bf16x8 __attribute__((ext_vector_type(8)));
typedef float f32x4 __attribute__((ext_vector_type(4)));

#define LOG2E 1.4426950408889634f

__device__ __forceinline__ f32x4 mfma16(bf16x8 a, bf16x8 b, f32x4 c) {
    return __builtin_amdgcn_mfma_f32_16x16x32_bf16(a, b, c, 0, 0, 0);
}

// async global->LDS, 16B per lane. LDS dest is wave-uniform base + lane*16.
__device__ __forceinline__ void async16(const void* g, void* l) {
    __builtin_amdgcn_global_load_lds(
        (const __attribute__((address_space(1))) void*)g,
        (__attribute__((address_space(3))) void*)l, 16, 0, 0);
}

// ---------------------------------------------------------------------------
// prep_w: W{1,2}t[n][k] = (sum_c W_reduce[k][c] * W_qkv[c][n]) * colscale(n)
// ---------------------------------------------------------------------------
__global__ __launch_bounds__(256) void prep_w(
    const float* __restrict__ Wr, const float* __restrict__ Wq,
    const float* __restrict__ w_ds, const float* __restrict__ w_uds,
    const float* __restrict__ b_uds,
    bf16* __restrict__ W1t, bf16* __restrict__ W2t, float* __restrict__ bias) {
    __shared__ float wq[256][17];
    const int t = threadIdx.x;
    const int k0 = blockIdx.x * 64, n0 = blockIdx.y * 16, z = blockIdx.z;
#pragma unroll
    for (int i = 0; i < 16; i++) {
        int c = i * 16 + (t >> 4);
        wq[c][t & 15] = Wq[c * 768 + n0 + (t & 15)];
    }
    __syncthreads();
    const int j = t & 15, n = n0 + j;
    const float rs = 0.17677669529663687f;  // 1/sqrt(32)
    float scale, bv;
    if (z == 0) {
        scale = (n < 256) ? w_ds[n] * rs : 1.f; bv = 0.f;
    } else if (n < 256) {
        scale = w_uds[n] * rs; bv = b_uds[n] * rs;
    } else if (n < 512) {
        scale = w_uds[n - 256]; bv = b_uds[n - 256];
    } else {
        scale = 1.f; bv = 0.f;
    }
    bf16* Wt = z ? W2t : W1t;
#pragma unroll 1
    for (int i = 0; i < 4; i++) {
        int k = k0 + (t >> 4) * 4 + i;
        float acc = 0.f;
        for (int c = 0; c < 256; c++) acc = fmaf(Wr[k * 256 + c], wq[c][j], acc);
        Wt[n * 512 + k] = (bf16)(acc * scale);
    }
    if (blockIdx.x == 0 && (t >> 4) == 0) bias[z * 768 + n] = bv;
}

// Wpt[n][k] = W_proj[k][n], bf16.  grid 512 blocks x 256 thr.
__global__ void prep_wp(const float* __restrict__ Wp, bf16* __restrict__ Wpt) {
    const int n = blockIdx.x, k = threadIdx.x;
    Wpt[n * 256 + k] = (bf16)Wp[k * 512 + n];
}

// ---------------------------------------------------------------------------
// xcast: fp32 -> bf16, vectorized 8/thread, grid (2048, 2).
// ---------------------------------------------------------------------------
__global__ __launch_bounds__(256) void xcast(const float* __restrict__ X1,
                                             const float* __restrict__ X2,
                                             bf16* __restrict__ O1,
                                             bf16* __restrict__ O2) {
    const float* X = blockIdx.y ? X2 : X1;
    bf16* O = blockIdx.y ? O2 : O1;
    const long total = 37879808;  // 73984 * 512
    const long stride = (long)gridDim.x * 256 * 8;
    for (long i = ((long)blockIdx.x * 256 + threadIdx.x) * 8; i < total; i += stride) {
        float4 a = *(const float4*)&X[i];
        float4 b = *(const float4*)&X[i + 4];
        bf16x8 w = {(bf16)a.x, (bf16)a.y, (bf16)a.z, (bf16)a.w,
                    (bf16)b.x, (bf16)b.y, (bf16)b.z, (bf16)b.w};
        *(bf16x8*)&O[i] = w;
    }
}

// ---------------------------------------------------------------------------
// gemm8: 256x256 tile, BK=64, 8 waves (512 thr), 4 phases per K-tile with
// counted vmcnt (T3+T4), XOR chunk-swizzled LDS (T2), setprio (T5).
//   Out[m][n] = sum_k A[m][k]*B[n][k] + bias[n]
// LDS 128KB: Lf[buf(2)][op(2)][kk(2)][256 rows][32 elems], rows' 16B chunk c
// stored at slot c ^ ((row>>1)&3)  (2-way bank conflict = free, m136).
// Staging: global_load_lds, linear LDS dest; inverse-swizzle on global source
// (rule 21).  Issue order per tile: A-kk0(h0,h1), B-kk0(h0,h1), A-kk1(2),
// B-kk1(2)  -> vmcnt(4) at phase0/2 guarantees exactly the kk-half needed.
// ---------------------------------------------------------------------------
template <int KT, int KS, int LDO, int OUTF32>
__device__ __forceinline__ void gemm8(const bf16* __restrict__ A,
                                      const bf16* __restrict__ B,
                                      const float* __restrict__ biasp,
                                      void* __restrict__ OutP, bf16* Lf) {
    const int tid = threadIdx.x;
    const int lane = tid & 63, wave = tid >> 6;
    const int ln = lane & 15, quad = lane >> 4;
    const int wm = wave >> 2, wn = wave & 3;  // wave tile rows wm*128, cols wn*64
    const int bn = blockIdx.x * 256, bm = blockIdx.y * 256;
    f32x4 acc[8][4] = {};
    float bi[4];
#pragma unroll
    for (int nr = 0; nr < 4; nr++) bi[nr] = biasp[bn + wn * 64 + nr * 16 + ln];

    // staging: thread -> row tid>>2 (0..127) of half h, global chunk inverse-swizzled
    const int srow = tid >> 2;
    const int schunk = ((tid & 3) ^ ((tid >> 3) & 3)) * 8;
    // read-side swizzled chunk (elems): global chunk q lives at slot q^((row>>1)&3)
    const int rq = (quad ^ ((ln >> 1) & 3)) * 8;
    const int abase = (wm * 128 + ln) * 32 + rq;           // + mr*512 + kk*8192 + buf*32768
    const int bbase = 16384 + (wn * 64 + ln) * 32 + rq;

    auto stA = [&](int buf, int kk, int h, int kb) {
        async16(&A[(long)(bm + h * 128 + srow) * KS + kb + kk * 32 + schunk],
                Lf + buf * 32768 + kk * 8192 + (h * 128 + wave * 16) * 32);
    };
    auto stB = [&](int buf, int kk, int h, int kb) {
        async16(&B[(long)(bn + h * 128 + srow) * KS + kb + kk * 32 + schunk],
                Lf + buf * 32768 + 16384 + kk * 8192 + (h * 128 + wave * 16) * 32);
    };

    // prologue: tile 0 -> buf 0, canonical order (defines vmcnt age groups)
    stA(0, 0, 0, 0); stA(0, 0, 1, 0); stB(0, 0, 0, 0); stB(0, 0, 1, 0);
    stA(0, 1, 0, 0); stA(0, 1, 1, 0); stB(0, 1, 0, 0); stB(0, 1, 1, 0);

#pragma unroll 1
    for (int kt = 0; kt < KT; ++kt) {
        const int cb = kt & 1, nb = cb ^ 1, kb = (kt + 1) * 64;
        const bool pf = (kt + 1) < KT;
        const int aoff = cb * 32768 + abase;
        const int boff = cb * 32768 + bbase;
        bf16x8 aF[4], bF[4], aG[4];
        // ---- phase 0: kk0, m-reps 0-3 (needs oldest-4 = A/B kk0)
        asm volatile("s_waitcnt vmcnt(4)" ::: "memory");
        __builtin_amdgcn_s_barrier();
        asm volatile("" ::: "memory");
#pragma unroll
        for (int i = 0; i < 4; i++) aF[i] = *(const bf16x8*)&Lf[aoff + i * 512];
#pragma unroll
        for (int i = 0; i < 4; i++) bF[i] = *(const bf16x8*)&Lf[boff + i * 512];
        if (pf) { stA(nb, 0, 0, kb); stA(nb, 0, 1, kb); }
        __builtin_amdgcn_s_setprio(1);
#pragma unroll
        for (int i = 0; i < 4; i++)
#pragma unroll
            for (int j = 0; j < 4; j++) acc[i][j] = mfma16(aF[i], bF[j], acc[i][j]);
        __builtin_amdgcn_s_setprio(0);
        // ---- phase 1: kk0, m-reps 4-7 (bF reused in regs)
        asm volatile("" ::: "memory");
        __builtin_amdgcn_s_barrier();
        asm volatile("" ::: "memory");
#pragma unroll
        for (int i = 0; i < 4; i++) aG[i] = *(const bf16x8*)&Lf[aoff + (i + 4) * 512];
        if (pf) { stB(nb, 0, 0, kb); stB(nb, 0, 1, kb); }
        __builtin_amdgcn_s_setprio(1);
#pragma unroll
        for (int i = 0; i < 4; i++)
#pragma unroll
            for (int j = 0; j < 4; j++) acc[i + 4][j] = mfma16(aG[i], bF[j], acc[i + 4][j]);
        __builtin_amdgcn_s_setprio(0);
        // ---- phase 2: kk1, m-reps 0-3 (needs A/B kk1; last tile drains)
        if (pf) asm volatile("s_waitcnt vmcnt(4)" ::: "memory");
        else    asm volatile("s_waitcnt vmcnt(0)" ::: "memory");
        __builtin_amdgcn_s_barrier();
        asm volatile("" ::: "memory");
#pragma unroll
        for (int i = 0; i < 4; i++) aF[i] = *(const bf16x8*)&Lf[aoff + 8192 + i * 512];
#pragma unroll
        for (int i = 0; i < 4; i++) bF[i] = *(const bf16x8*)&Lf[boff + 8192 + i * 512];
        if (pf) { stA(nb, 1, 0, kb); stA(nb, 1, 1, kb); }
        __builtin_amdgcn_s_setprio(1);
#pragma unroll
        for (int i = 0; i < 4; i++)
#pragma unroll
            for (int j = 0; j < 4; j++) acc[i][j] = mfma16(aF[i], bF[j], acc[i][j]);
        __builtin_amdgcn_s_setprio(0);
        // ---- phase 3: kk1, m-reps 4-7
        asm volatile("" ::: "memory");
        __builtin_amdgcn_s_barrier();
        asm volatile("" ::: "memory");
#pragma unroll
        for (int i = 0; i < 4; i++) aG[i] = *(const bf16x8*)&Lf[aoff + 8192 + (i + 4) * 512];
        if (pf) { stB(nb, 1, 0, kb); stB(nb, 1, 1, kb); }
        __builtin_amdgcn_s_setprio(1);
#pragma unroll
        for (int i = 0; i < 4; i++)
#pragma unroll
            for (int j = 0; j < 4; j++) acc[i + 4][j] = mfma16(aG[i], bF[j], acc[i + 4][j]);
        __builtin_amdgcn_s_setprio(0);
    }
    // epilogue
#pragma unroll
    for (int i = 0; i < 8; i++)
#pragma unroll
        for (int j = 0; j < 4; j++) {
            const int col = bn + wn * 64 + j * 16 + ln;
            const long row0 = bm + wm * 128 + i * 16 + quad * 4;
            if (OUTF32) {
                float* Y = (float*)OutP;
#pragma unroll
                for (int r = 0; r < 4; r++)
                    Y[(row0 + r) * LDO + col] = acc[i][j][r] + bi[j];
            } else {
                bf16* Y = (bf16*)OutP;
#pragma unroll
                for (int r = 0; r < 4; r++)
                    Y[(row0 + r) * LDO + col] = (bf16)(acc[i][j][r] + bi[j]);
            }
        }
}

// qkv: M=73984 K=512 N=768, grid (3, 289) x 512 thr
__global__ __launch_bounds__(512, 2) void gemm_qkv8(
    const bf16* __restrict__ X, const bf16* __restrict__ Wt,
    const float* __restrict__ biasp, bf16* __restrict__ Out) {
    __shared__ __attribute__((aligned(16))) bf16 L[65536];  // 128 KB
    gemm8<8, 512, 768, 0>(X, Wt, biasp, Out, L);
}

// proj: M=73984 K=256 N=512, grid (2, 289) x 512 thr
__global__ __launch_bounds__(512, 2) void gemm_proj8(
    const bf16* __restrict__ Ain, const bf16* __restrict__ Wpt,
    const float* __restrict__ bp, float* __restrict__ Y) {
    __shared__ __attribute__((aligned(16))) bf16 L[65536];  // 128 KB
    gemm8<4, 256, 512, 1>(Ain, Wpt, bp, Y, L);
}

// ---------------------------------------------------------------------------
// attn: unchanged (per (chunk, batch) block, 4 waves, wave-private LDS).
// ---------------------------------------------------------------------------
__global__ __launch_bounds__(256) void attn(const bf16* __restrict__ QKV,
                                            bf16* __restrict__ O) {
    __shared__ __attribute__((aligned(16))) bf16 vT[4][32 * 104];
    __shared__ __attribute__((aligned(16))) bf16 P[4][16 * 104];
    const int tid = threadIdx.x;
    const int lane = tid & 63, wave = tid >> 6;
    const int ln = lane & 15, quad = lane >> 4;
    const int chunk = blockIdx.x, b = blockIdx.y;
    const int s = chunk * 73;
    const int mc = min(289 - s, 73);  // chunk length (73,73,73,70)
    const int rowbase = b * 289 + s;
    bf16* vTw = &vT[wave][0];
    bf16* Pw = &P[wave][0];
    const f32x4 zero4 = {0.f, 0.f, 0.f, 0.f};

    {
        bf16x4 z = {(bf16)0.f, (bf16)0.f, (bf16)0.f, (bf16)0.f};
        *(bf16x4*)&Pw[(lane >> 2) * 104 + 80 + (lane & 3) * 4] = z;
    }

#pragma unroll 1
    for (int hi = 0; hi < 2; hi++) {
        const int h = wave + hi * 4;
        const int cq = h * 32, ck = 256 + h * 32, cv = 512 + h * 32;

#pragma unroll
        for (int p5 = 0; p5 < 6; p5++) {
            int m = p5 * 16 + (lane >> 2);
            int mr = min(m, mc - 1);
            bf16x8 v8 = *(const bf16x8*)&QKV[(rowbase + mr) * 768 + cv + (lane & 3) * 8];
            int d0 = (lane & 3) * 8;
#pragma unroll
            for (int j = 0; j < 8; j++) vTw[(d0 + j) * 104 + m] = v8[j];
        }
        bf16x8 kf[5];
#pragma unroll
        for (int mt = 0; mt < 5; mt++) {
            int mr = min(mt * 16 + ln, mc - 1);
            kf[mt] = *(const bf16x8*)&QKV[(rowbase + mr) * 768 + ck + quad * 8];
        }
        bf16x8 vf[2][3];
#pragma unroll
        for (int dt = 0; dt < 2; dt++)
#pragma unroll
            for (int mk = 0; mk < 3; mk++)
                vf[dt][mk] = *(const bf16x8*)&vTw[(dt * 16 + ln) * 104 + mk * 32 + quad * 8];

#pragma unroll 1
        for (int nt = 0; nt < 5; nt++) {
            int qr = min(nt * 16 + ln, mc - 1);
            bf16x8 qf = *(const bf16x8*)&QKV[(rowbase + qr) * 768 + cq + quad * 8];
            f32x4 S[5];
#pragma unroll
            for (int mt = 0; mt < 5; mt++) S[mt] = mfma16(qf, kf[mt], zero4);
#pragma unroll
            for (int mt = 0; mt < 5; mt++)
                if (mt * 16 + ln >= mc) {
                    S[mt][0] = -1e30f; S[mt][1] = -1e30f;
                    S[mt][2] = -1e30f; S[mt][3] = -1e30f;
                }
            float mxv[4], sm[4];
#pragma unroll
            for (int r = 0; r < 4; r++) {
                float m0 = S[0][r];
#pragma unroll
                for (int mt = 1; mt < 5; mt++) m0 = fmaxf(m0, S[mt][r]);
                m0 = fmaxf(m0, __shfl_xor(m0, 1));
                m0 = fmaxf(m0, __shfl_xor(m0, 2));
                m0 = fmaxf(m0, __shfl_xor(m0, 4));
                m0 = fmaxf(m0, __shfl_xor(m0, 8));
                mxv[r] = m0;
                sm[r] = 0.f;
            }
#pragma unroll
            for (int mt = 0; mt < 5; mt++)
#pragma unroll
                for (int r = 0; r < 4; r++) {
                    float p = exp2f((S[mt][r] - mxv[r]) * LOG2E);
                    sm[r] += p;
                    Pw[(quad * 4 + r) * 104 + mt * 16 + ln] = (bf16)p;
                }
#pragma unroll
            for (int r = 0; r < 4; r++) {
                float t = sm[r];
                t += __shfl_xor(t, 1);
                t += __shfl_xor(t, 2);
                t += __shfl_xor(t, 4);
                t += __shfl_xor(t, 8);
                sm[r] = 1.0f / t;
            }
            f32x4 o0 = zero4, o1 = zero4;
#pragma unroll
            for (int mk = 0; mk < 3; mk++) {
                bf16x8 pa = *(const bf16x8*)&Pw[ln * 104 + mk * 32 + quad * 8];
                o0 = mfma16(pa, vf[0][mk], o0);
                o1 = mfma16(pa, vf[1][mk], o1);
            }
#pragma unroll
            for (int r = 0; r < 4; r++) {
                int nl = nt * 16 + quad * 4 + r;
                if (nl < mc) {
                    int orow = (rowbase + nl) * 256 + h * 32;
                    O[orow + ln] = (bf16)(o0[r] * sm[r]);
                    O[orow + 16 + ln] = (bf16)(o1[r] * sm[r]);
                }
            }
        }
    }
}

// ---------------------------------------------------------------------------
// Buffer plan:
//   ws:   W1t 786432 | W2t 786432 | Wpt 262144 | bias 6144 | ob 37879808
//   d_out: [0:75759616) Xb1 | [75759616:151519232) Xb2 | [151519232:...) qkv
//   Order: casts first; both qkv GEMMs consume Xb before proj overwrites y1;
//   qkv(br0) consumed by attn(br0) before gemm_qkv8(br1) rewrites it.
// ---------------------------------------------------------------------------
extern "C" void kernel_launch(void* const* d_in, const int* in_sizes, int n_in,
                              void* d_out, int out_size, void* d_ws, size_t ws_size,
                              hipStream_t stream) {
    (void)in_sizes; (void)n_in; (void)out_size; (void)ws_size;
    const float* x1 = (const float*)d_in[0];
    const float* x2 = (const float*)d_in[1];
    const float* Wr = (const float*)d_in[2];
    const float* Wq = (const float*)d_in[3];
    const float* Wp = (const float*)d_in[4];
    const float* bp = (const float*)d_in[5];
    const float* w_ds = (const float*)d_in[6];
    const float* w_uds = (const float*)d_in[7];
    const float* b_uds = (const float*)d_in[8];

    char* ws = (char*)d_ws;
    bf16* W1t = (bf16*)(ws);                     //  786432 B
    bf16* W2t = (bf16*)(ws + 786432);            //  786432 B
    bf16* Wpt = (bf16*)(ws + 1572864);           //  262144 B
    float* bias = (float*)(ws + 1835008);        //    6144 B
    bf16* ob = (bf16*)(ws + 1841152);            // 37879808 B
    float* out = (float*)d_out;
    char* outc = (char*)d_out;
    bf16* Xb1 = (bf16*)(outc);                   // 75759616 B
    bf16* Xb2 = (bf16*)(outc + 75759616);        // 75759616 B
    bf16* qkv = (bf16*)(outc + 151519232);       // 113639424 B

    prep_w<<<dim3(8, 48, 2), 256, 0, stream>>>(Wr, Wq, w_ds, w_uds, b_uds, W1t, W2t, bias);
    prep_wp<<<dim3(512), 256, 0, stream>>>(Wp, Wpt);
    xcast<<<dim3(2048, 2), 256, 0, stream>>>(x1, x2, Xb1, Xb2);

    gemm_qkv8<<<dim3(3, 289), 512, 0, stream>>>(Xb1, W1t, bias, qkv);
    attn<<<dim3(4, 256), 256, 0, stream>>>(qkv, ob);
    gemm_qkv8<<<dim3(3, 289), 512, 0, stream>>>(Xb2, W2t, bias + 768, qkv);
    gemm_proj8<<<dim3(2, 289), 512, 0, stream>>>(ob, Wpt, bp, out);
    attn<<<dim3(4, 256), 256, 0, stream>>>(qkv, ob);
    gemm_proj8<<<dim3(2, 289), 512, 0, stream>>>(ob, Wpt, bp, out + (size_t)37879808);
}

// Round 4
// 846.728 us; speedup vs baseline: 1.1080x; 1.0594x over previous
//
#include <hip/hip_runtime.h>

typedef __bf16 bf16;
typedef bf16 bf16x4 __attribute__((ext_vector_type(4)));
typedef bf16 bf16x8 __attribute__((ext_vector_type(8)));
typedef float f32x4 __attribute__((ext_vector_type(4)));

#define LOG2E 1.4426950408889634f

__device__ __forceinline__ f32x4 mfma16(bf16x8 a, bf16x8 b, f32x4 c) {
    return __builtin_amdgcn_mfma_f32_16x16x32_bf16(a, b, c, 0, 0, 0);
}

// async global->LDS, 16B per lane. LDS dest is wave-uniform base + lane*16.
__device__ __forceinline__ void async16(const void* g, void* l) {
    __builtin_amdgcn_global_load_lds(
        (const __attribute__((address_space(1))) void*)g,
        (__attribute__((address_space(3))) void*)l, 16, 0, 0);
}

// ---------------------------------------------------------------------------
// megaprep: one launch fusing
//   blocks [0,768):    prep_w   (8 k-blocks x 48 n-blocks x 2 branches)
//   blocks [768,1280): prep_wp  (512 n-rows)
//   blocks [1280,5376): xcast   (2048 blocks x 2 images)
// ---------------------------------------------------------------------------
__global__ __launch_bounds__(256) void megaprep(
    const float* __restrict__ Wr, const float* __restrict__ Wq,
    const float* __restrict__ w_ds, const float* __restrict__ w_uds,
    const float* __restrict__ b_uds, const float* __restrict__ Wp,
    const float* __restrict__ x1, const float* __restrict__ x2,
    bf16* __restrict__ W1t, bf16* __restrict__ W2t, bf16* __restrict__ Wpt,
    float* __restrict__ bias, bf16* __restrict__ Xb1, bf16* __restrict__ Xb2) {
    __shared__ float wq[256][17];
    const int id = blockIdx.x;
    const int t = threadIdx.x;
    if (id < 768) {
        // ---- prep_w: W{1,2}t[n][k] = (sum_c Wr[k][c]*Wq[c][n]) * colscale(n)
        const int kx = id & 7, ny = (id >> 3) % 48, z = id / 384;
        const int k0 = kx * 64, n0 = ny * 16;
#pragma unroll
        for (int i = 0; i < 16; i++) {
            int c = i * 16 + (t >> 4);
            wq[c][t & 15] = Wq[c * 768 + n0 + (t & 15)];
        }
        __syncthreads();
        const int j = t & 15, n = n0 + j;
        const float rs = 0.17677669529663687f;  // 1/sqrt(32)
        float scale, bv;
        if (z == 0) {
            scale = (n < 256) ? w_ds[n] * rs : 1.f; bv = 0.f;
        } else if (n < 256) {
            scale = w_uds[n] * rs; bv = b_uds[n] * rs;
        } else if (n < 512) {
            scale = w_uds[n - 256]; bv = b_uds[n - 256];
        } else {
            scale = 1.f; bv = 0.f;
        }
        bf16* Wt = z ? W2t : W1t;
#pragma unroll 1
        for (int i = 0; i < 4; i++) {
            int k = k0 + (t >> 4) * 4 + i;
            float acc = 0.f;
            for (int c = 0; c < 256; c++) acc = fmaf(Wr[k * 256 + c], wq[c][j], acc);
            Wt[n * 512 + k] = (bf16)(acc * scale);
        }
        if (kx == 0 && (t >> 4) == 0) bias[z * 768 + n] = bv;
    } else if (id < 1280) {
        // ---- prep_wp: Wpt[n][k] = W_proj[k][n]
        const int n = id - 768, k = t;
        Wpt[n * 256 + k] = (bf16)Wp[k * 512 + n];
    } else {
        // ---- xcast: fp32 -> bf16, 8 elems/thread, grid-stride
        const int i0 = id - 1280;
        const int by = i0 >> 11, bx = i0 & 2047;
        const float* X = by ? x2 : x1;
        bf16* O = by ? Xb2 : Xb1;
        const long total = 37879808;  // 73984 * 512
        const long stride = (long)2048 * 256 * 8;
        for (long i = ((long)bx * 256 + t) * 8; i < total; i += stride) {
            float4 a = *(const float4*)&X[i];
            float4 b = *(const float4*)&X[i + 4];
            bf16x8 w = {(bf16)a.x, (bf16)a.y, (bf16)a.z, (bf16)a.w,
                        (bf16)b.x, (bf16)b.y, (bf16)b.z, (bf16)b.w};
            *(bf16x8*)&O[i] = w;
        }
    }
}

// ---------------------------------------------------------------------------
// gemm8: 256x256 tile, BK=64, 8 waves (512 thr), 4 phases per K-tile with
// counted vmcnt (T3+T4), XOR chunk-swizzled LDS (T2), setprio (T5).
//   Out[m][n] = sum_k A[m][k]*B[n][k] + bias[n]
// (verified round 3; internals unchanged)
// ---------------------------------------------------------------------------
template <int KT, int KS, int LDO, int OUTF32>
__device__ __forceinline__ void gemm8(const bf16* __restrict__ A,
                                      const bf16* __restrict__ B,
                                      const float* __restrict__ biasp,
                                      void* __restrict__ OutP, bf16* Lf) {
    const int tid = threadIdx.x;
    const int lane = tid & 63, wave = tid >> 6;
    const int ln = lane & 15, quad = lane >> 4;
    const int wm = wave >> 2, wn = wave & 3;
    const int bn = blockIdx.x * 256, bm = blockIdx.y * 256;
    f32x4 acc[8][4] = {};
    float bi[4];
#pragma unroll
    for (int nr = 0; nr < 4; nr++) bi[nr] = biasp[bn + wn * 64 + nr * 16 + ln];

    const int srow = tid >> 2;
    const int schunk = ((tid & 3) ^ ((tid >> 3) & 3)) * 8;
    const int rq = (quad ^ ((ln >> 1) & 3)) * 8;
    const int abase = (wm * 128 + ln) * 32 + rq;
    const int bbase = 16384 + (wn * 64 + ln) * 32 + rq;

    auto stA = [&](int buf, int kk, int h, int kb) {
        async16(&A[(long)(bm + h * 128 + srow) * KS + kb + kk * 32 + schunk],
                Lf + buf * 32768 + kk * 8192 + (h * 128 + wave * 16) * 32);
    };
    auto stB = [&](int buf, int kk, int h, int kb) {
        async16(&B[(long)(bn + h * 128 + srow) * KS + kb + kk * 32 + schunk],
                Lf + buf * 32768 + 16384 + kk * 8192 + (h * 128 + wave * 16) * 32);
    };

    stA(0, 0, 0, 0); stA(0, 0, 1, 0); stB(0, 0, 0, 0); stB(0, 0, 1, 0);
    stA(0, 1, 0, 0); stA(0, 1, 1, 0); stB(0, 1, 0, 0); stB(0, 1, 1, 0);

#pragma unroll 1
    for (int kt = 0; kt < KT; ++kt) {
        const int cb = kt & 1, nb = cb ^ 1, kb = (kt + 1) * 64;
        const bool pf = (kt + 1) < KT;
        const int aoff = cb * 32768 + abase;
        const int boff = cb * 32768 + bbase;
        bf16x8 aF[4], bF[4], aG[4];
        // ---- phase 0: kk0, m-reps 0-3
        asm volatile("s_waitcnt vmcnt(4)" ::: "memory");
        __builtin_amdgcn_s_barrier();
        asm volatile("" ::: "memory");
#pragma unroll
        for (int i = 0; i < 4; i++) aF[i] = *(const bf16x8*)&Lf[aoff + i * 512];
#pragma unroll
        for (int i = 0; i < 4; i++) bF[i] = *(const bf16x8*)&Lf[boff + i * 512];
        if (pf) { stA(nb, 0, 0, kb); stA(nb, 0, 1, kb); }
        __builtin_amdgcn_s_setprio(1);
#pragma unroll
        for (int i = 0; i < 4; i++)
#pragma unroll
            for (int j = 0; j < 4; j++) acc[i][j] = mfma16(aF[i], bF[j], acc[i][j]);
        __builtin_amdgcn_s_setprio(0);
        // ---- phase 1: kk0, m-reps 4-7
        asm volatile("" ::: "memory");
        __builtin_amdgcn_s_barrier();
        asm volatile("" ::: "memory");
#pragma unroll
        for (int i = 0; i < 4; i++) aG[i] = *(const bf16x8*)&Lf[aoff + (i + 4) * 512];
        if (pf) { stB(nb, 0, 0, kb); stB(nb, 0, 1, kb); }
        __builtin_amdgcn_s_setprio(1);
#pragma unroll
        for (int i = 0; i < 4; i++)
#pragma unroll
            for (int j = 0; j < 4; j++) acc[i + 4][j] = mfma16(aG[i], bF[j], acc[i + 4][j]);
        __builtin_amdgcn_s_setprio(0);
        // ---- phase 2: kk1, m-reps 0-3
        if (pf) asm volatile("s_waitcnt vmcnt(4)" ::: "memory");
        else    asm volatile("s_waitcnt vmcnt(0)" ::: "memory");
        __builtin_amdgcn_s_barrier();
        asm volatile("" ::: "memory");
#pragma unroll
        for (int i = 0; i < 4; i++) aF[i] = *(const bf16x8*)&Lf[aoff + 8192 + i * 512];
#pragma unroll
        for (int i = 0; i < 4; i++) bF[i] = *(const bf16x8*)&Lf[boff + 8192 + i * 512];
        if (pf) { stA(nb, 1, 0, kb); stA(nb, 1, 1, kb); }
        __builtin_amdgcn_s_setprio(1);
#pragma unroll
        for (int i = 0; i < 4; i++)
#pragma unroll
            for (int j = 0; j < 4; j++) acc[i][j] = mfma16(aF[i], bF[j], acc[i][j]);
        __builtin_amdgcn_s_setprio(0);
        // ---- phase 3: kk1, m-reps 4-7
        asm volatile("" ::: "memory");
        __builtin_amdgcn_s_barrier();
        asm volatile("" ::: "memory");
#pragma unroll
        for (int i = 0; i < 4; i++) aG[i] = *(const bf16x8*)&Lf[aoff + 8192 + (i + 4) * 512];
        if (pf) { stB(nb, 1, 0, kb); stB(nb, 1, 1, kb); }
        __builtin_amdgcn_s_setprio(1);
#pragma unroll
        for (int i = 0; i < 4; i++)
#pragma unroll
            for (int j = 0; j < 4; j++) acc[i + 4][j] = mfma16(aG[i], bF[j], acc[i + 4][j]);
        __builtin_amdgcn_s_setprio(0);
    }
    // epilogue
#pragma unroll
    for (int i = 0; i < 8; i++)
#pragma unroll
        for (int j = 0; j < 4; j++) {
            const int col = bn + wn * 64 + j * 16 + ln;
            const long row0 = bm + wm * 128 + i * 16 + quad * 4;
            if (OUTF32) {
                float* Y = (float*)OutP;
#pragma unroll
                for (int r = 0; r < 4; r++)
                    Y[(row0 + r) * LDO + col] = acc[i][j][r] + bi[j];
            } else {
                bf16* Y = (bf16*)OutP;
#pragma unroll
                for (int r = 0; r < 4; r++)
                    Y[(row0 + r) * LDO + col] = (bf16)(acc[i][j][r] + bi[j]);
            }
        }
}

// qkv: M=73984 K=512 N=768, grid (3, 289, nz) x 512 thr; z selects branch
__global__ __launch_bounds__(512, 2) void gemm_qkv8(
    const bf16* __restrict__ X1, const bf16* __restrict__ X2,
    const bf16* __restrict__ W1t, const bf16* __restrict__ W2t,
    const float* __restrict__ biasp, bf16* __restrict__ O1,
    bf16* __restrict__ O2) {
    __shared__ __attribute__((aligned(16))) bf16 L[65536];  // 128 KB
    const int z = blockIdx.z;
    gemm8<8, 512, 768, 0>(z ? X2 : X1, z ? W2t : W1t, biasp + z * 768,
                          z ? O2 : O1, L);
}

// proj: M=73984 K=256 N=512, grid (2, 289, nz) x 512 thr; z selects branch
__global__ __launch_bounds__(512, 2) void gemm_proj8(
    const bf16* __restrict__ A1, const bf16* __restrict__ A2,
    const bf16* __restrict__ Wpt, const float* __restrict__ bp,
    float* __restrict__ Y) {
    __shared__ __attribute__((aligned(16))) bf16 L[65536];  // 128 KB
    const int z = blockIdx.z;
    gemm8<4, 256, 512, 1>(z ? A2 : A1, Wpt, bp, Y + (size_t)z * 37879808, L);
}

// ---------------------------------------------------------------------------
// attn: per (chunk, batch, branch) block, 4 waves, wave-private LDS.
// ---------------------------------------------------------------------------
__global__ __launch_bounds__(256) void attn(const bf16* __restrict__ QKV1,
                                            const bf16* __restrict__ QKV2,
                                            bf16* __restrict__ O1,
                                            bf16* __restrict__ O2) {
    __shared__ __attribute__((aligned(16))) bf16 vT[4][32 * 104];
    __shared__ __attribute__((aligned(16))) bf16 P[4][16 * 104];
    const int z = blockIdx.z;
    const bf16* QKV = z ? QKV2 : QKV1;
    bf16* O = z ? O2 : O1;
    const int tid = threadIdx.x;
    const int lane = tid & 63, wave = tid >> 6;
    const int ln = lane & 15, quad = lane >> 4;
    const int chunk = blockIdx.x, b = blockIdx.y;
    const int s = chunk * 73;
    const int mc = min(289 - s, 73);  // chunk length (73,73,73,70)
    const int rowbase = b * 289 + s;
    bf16* vTw = &vT[wave][0];
    bf16* Pw = &P[wave][0];
    const f32x4 zero4 = {0.f, 0.f, 0.f, 0.f};

    {
        bf16x4 zz = {(bf16)0.f, (bf16)0.f, (bf16)0.f, (bf16)0.f};
        *(bf16x4*)&Pw[(lane >> 2) * 104 + 80 + (lane & 3) * 4] = zz;
    }

#pragma unroll 1
    for (int hi = 0; hi < 2; hi++) {
        const int h = wave + hi * 4;
        const int cq = h * 32, ck = 256 + h * 32, cv = 512 + h * 32;

#pragma unroll
        for (int p5 = 0; p5 < 6; p5++) {
            int m = p5 * 16 + (lane >> 2);
            int mr = min(m, mc - 1);
            bf16x8 v8 = *(const bf16x8*)&QKV[(rowbase + mr) * 768 + cv + (lane & 3) * 8];
            int d0 = (lane & 3) * 8;
#pragma unroll
            for (int j = 0; j < 8; j++) vTw[(d0 + j) * 104 + m] = v8[j];
        }
        bf16x8 kf[5];
#pragma unroll
        for (int mt = 0; mt < 5; mt++) {
            int mr = min(mt * 16 + ln, mc - 1);
            kf[mt] = *(const bf16x8*)&QKV[(rowbase + mr) * 768 + ck + quad * 8];
        }
        bf16x8 vf[2][3];
#pragma unroll
        for (int dt = 0; dt < 2; dt++)
#pragma unroll
            for (int mk = 0; mk < 3; mk++)
                vf[dt][mk] = *(const bf16x8*)&vTw[(dt * 16 + ln) * 104 + mk * 32 + quad * 8];

#pragma unroll 1
        for (int nt = 0; nt < 5; nt++) {
            int qr = min(nt * 16 + ln, mc - 1);
            bf16x8 qf = *(const bf16x8*)&QKV[(rowbase + qr) * 768 + cq + quad * 8];
            f32x4 S[5];
#pragma unroll
            for (int mt = 0; mt < 5; mt++) S[mt] = mfma16(qf, kf[mt], zero4);
#pragma unroll
            for (int mt = 0; mt < 5; mt++)
                if (mt * 16 + ln >= mc) {
                    S[mt][0] = -1e30f; S[mt][1] = -1e30f;
                    S[mt][2] = -1e30f; S[mt][3] = -1e30f;
                }
            float mxv[4], sm[4];
#pragma unroll
            for (int r = 0; r < 4; r++) {
                float m0 = S[0][r];
#pragma unroll
                for (int mt = 1; mt < 5; mt++) m0 = fmaxf(m0, S[mt][r]);
                m0 = fmaxf(m0, __shfl_xor(m0, 1));
                m0 = fmaxf(m0, __shfl_xor(m0, 2));
                m0 = fmaxf(m0, __shfl_xor(m0, 4));
                m0 = fmaxf(m0, __shfl_xor(m0, 8));
                mxv[r] = m0;
                sm[r] = 0.f;
            }
#pragma unroll
            for (int mt = 0; mt < 5; mt++)
#pragma unroll
                for (int r = 0; r < 4; r++) {
                    float p = exp2f((S[mt][r] - mxv[r]) * LOG2E);
                    sm[r] += p;
                    Pw[(quad * 4 + r) * 104 + mt * 16 + ln] = (bf16)p;
                }
#pragma unroll
            for (int r = 0; r < 4; r++) {
                float t = sm[r];
                t += __shfl_xor(t, 1);
                t += __shfl_xor(t, 2);
                t += __shfl_xor(t, 4);
                t += __shfl_xor(t, 8);
                sm[r] = 1.0f / t;
            }
            f32x4 o0 = zero4, o1 = zero4;
#pragma unroll
            for (int mk = 0; mk < 3; mk++) {
                bf16x8 pa = *(const bf16x8*)&Pw[ln * 104 + mk * 32 + quad * 8];
                o0 = mfma16(pa, vf[0][mk], o0);
                o1 = mfma16(pa, vf[1][mk], o1);
            }
#pragma unroll
            for (int r = 0; r < 4; r++) {
                int nl = nt * 16 + quad * 4 + r;
                if (nl < mc) {
                    int orow = (rowbase + nl) * 256 + h * 32;
                    O[orow + ln] = (bf16)(o0[r] * sm[r]);
                    O[orow + 16 + ln] = (bf16)(o1[r] * sm[r]);
                }
            }
        }
    }
}

// ---------------------------------------------------------------------------
// Buffer plan.
//  ws (fills observed at 1.2 GB -> big path expected):
//   W1t 0 | W2t 786432 | Wpt 1572864 | bias 1835008 | ob1 1841152
//   Xb1 39720960 | Xb2 115480576 | qkv1 191240192 | qkv2 304879616
//   ob2 418519040 | end 456398848
//  Big path: 4 launches, branches merged via grid.z.
//  Fallback (ws < 456398848): serialized 7-launch plan using d_out scratch
//   (Xb1 [0,75.8M), Xb2 [75.8,151.5M), qkv [151.5,265.2M)), ob2 = ob1.
// ---------------------------------------------------------------------------
extern "C" void kernel_launch(void* const* d_in, const int* in_sizes, int n_in,
                              void* d_out, int out_size, void* d_ws, size_t ws_size,
                              hipStream_t stream) {
    (void)in_sizes; (void)n_in; (void)out_size;
    const float* x1 = (const float*)d_in[0];
    const float* x2 = (const float*)d_in[1];
    const float* Wr = (const float*)d_in[2];
    const float* Wq = (const float*)d_in[3];
    const float* Wp = (const float*)d_in[4];
    const float* bp = (const float*)d_in[5];
    const float* w_ds = (const float*)d_in[6];
    const float* w_uds = (const float*)d_in[7];
    const float* b_uds = (const float*)d_in[8];

    char* ws = (char*)d_ws;
    bf16* W1t = (bf16*)(ws);
    bf16* W2t = (bf16*)(ws + 786432);
    bf16* Wpt = (bf16*)(ws + 1572864);
    float* bias = (float*)(ws + 1835008);
    bf16* ob1 = (bf16*)(ws + 1841152);
    float* out = (float*)d_out;
    char* outc = (char*)d_out;

    if (ws_size >= (size_t)456398848) {
        bf16* Xb1 = (bf16*)(ws + 39720960);
        bf16* Xb2 = (bf16*)(ws + 115480576);
        bf16* qkv1 = (bf16*)(ws + 191240192);
        bf16* qkv2 = (bf16*)(ws + 304879616);
        bf16* ob2 = (bf16*)(ws + 418519040);
        megaprep<<<dim3(5376), 256, 0, stream>>>(Wr, Wq, w_ds, w_uds, b_uds, Wp,
                                                 x1, x2, W1t, W2t, Wpt, bias,
                                                 Xb1, Xb2);
        gemm_qkv8<<<dim3(3, 289, 2), 512, 0, stream>>>(Xb1, Xb2, W1t, W2t, bias,
                                                       qkv1, qkv2);
        attn<<<dim3(4, 256, 2), 256, 0, stream>>>(qkv1, qkv2, ob1, ob2);
        gemm_proj8<<<dim3(2, 289, 2), 512, 0, stream>>>(ob1, ob2, Wpt, bp, out);
    } else {
        bf16* Xb1 = (bf16*)(outc);
        bf16* Xb2 = (bf16*)(outc + 75759616);
        bf16* qkv = (bf16*)(outc + 151519232);
        megaprep<<<dim3(5376), 256, 0, stream>>>(Wr, Wq, w_ds, w_uds, b_uds, Wp,
                                                 x1, x2, W1t, W2t, Wpt, bias,
                                                 Xb1, Xb2);
        gemm_qkv8<<<dim3(3, 289, 1), 512, 0, stream>>>(Xb1, Xb1, W1t, W1t, bias,
                                                       qkv, qkv);
        attn<<<dim3(4, 256, 1), 256, 0, stream>>>(qkv, qkv, ob1, ob1);
        gemm_qkv8<<<dim3(3, 289, 1), 512, 0, stream>>>(Xb2, Xb2, W2t, W2t,
                                                       bias + 768, qkv, qkv);
        gemm_proj8<<<dim3(2, 289, 1), 512, 0, stream>>>(ob1, ob1, Wpt, bp, out);
        attn<<<dim3(4, 256, 1), 256, 0, stream>>>(qkv, qkv, ob1, ob1);
        gemm_proj8<<<dim3(2, 289, 1), 512, 0, stream>>>(ob1, ob1, Wpt, bp,
                                                        out + (size_t)37879808);
    }
}